// Round 10
// baseline (146.164 us; speedup 1.0000x reference)
//
#include <hip/hip_runtime.h>

#define NQn 10000
#define NSn 10000
#define Hh  32
#define FDIM  3840   // K(15) * 2*IN_CH(256)  — logical reduction dim
#define FDIMP 4096   // padded: f' = col*16 + k, k in [0,16), col in [0,256)

typedef _Float16 f16x8 __attribute__((ext_vector_type(8)));
typedef float    f32x4 __attribute__((ext_vector_type(4)));

__device__ __forceinline__ unsigned pack2h(float a, float b) {
  union { _Float16 h; unsigned short u; } ua, ub;
  ua.h = (_Float16)a; ub.h = (_Float16)b;
  return (unsigned)ua.u | ((unsigned)ub.u << 16);
}

// ---------------------------------------------------------------------------
// Prep (1138 blocks):
//   b <  625 : xh[i] = fp16(x[i])                (10000x128, vectorized)
//   b == 625 : xh row NSn = 0                    (shadow zero-row)
//   else     : wt[o][f'] = fp16(weights[orig(f')][o]) or 0 at k-pad
//              via LDS tile transpose; f' = col*16 + k, orig = k*256 + col
// ---------------------------------------------------------------------------
__global__ __launch_bounds__(256) void ekp_prep6(
    const float* __restrict__ w, const float* __restrict__ x,
    _Float16* __restrict__ wt, _Float16* __restrict__ xh)
{
  const int b = blockIdx.x, tid = threadIdx.x;
  if (b < 625) {
    size_t base = (size_t)b*2048 + (size_t)tid*8;
    float4 a0 = *reinterpret_cast<const float4*>(x + base);
    float4 a1 = *reinterpret_cast<const float4*>(x + base + 4);
    uint4 o;
    o.x = pack2h(a0.x, a0.y); o.y = pack2h(a0.z, a0.w);
    o.z = pack2h(a1.x, a1.y); o.w = pack2h(a1.z, a1.w);
    *reinterpret_cast<uint4*>(xh + base) = o;
  } else if (b == 625) {
    if (tid < 64)
      reinterpret_cast<unsigned*>(xh + (size_t)NSn*128)[tid] = 0u;
  } else {
    __shared__ _Float16 t[32][34];
    const int tt = b - 626;                 // 0..511
    const int f0 = (tt & 127) * 32;         // f' tile base
    const int o0 = (tt >> 7) * 32;          // out-channel tile base
    const int c = tid & 31, r0 = tid >> 5;
    #pragma unroll
    for (int p = 0; p < 4; ++p) {
      int r = r0 + p*8;
      int f = f0 + r;
      int k = f & 15, col = f >> 4;
      t[c][r] = (k < 15)
        ? (_Float16)w[(size_t)(k*256 + col)*128 + o0 + c]
        : (_Float16)0.f;
    }
    __syncthreads();
    #pragma unroll
    for (int p = 0; p < 4; ++p) {
      int r = r0 + p*8;
      wt[(size_t)(o0 + r)*FDIMP + f0 + c] = t[r][c];
    }
  }
}

// ---------------------------------------------------------------------------
// Stage 1i: r9's verified stage1h with ONE delta: wf stored in the padded
// k-major layout wf[n][col*16 + k] as 4 uint2 stores/thread (no k<15 guards;
// pad row k=15 is MFMA-zero since sWb row 15 is zeroed).
// ---------------------------------------------------------------------------
__global__ __launch_bounds__(256, 4) void ekp_stage1i(
    const float* __restrict__ q_pts, const float* __restrict__ s_pts,
    const int*   __restrict__ nbi,   const unsigned short* __restrict__ xh,
    const float* __restrict__ q_lrf, const float* __restrict__ s_lrf,
    const float* __restrict__ kp,    const float* __restrict__ mlp_w,
    const float* __restrict__ mlp_b, _Float16* __restrict__ wf_out)
{
  const int n = blockIdx.x;
  const int tid = threadIdx.x;
  const int lane = tid & 63;
  const int wv = tid >> 6;          // wave id == q
  const int l15 = lane & 15, lg = lane >> 4;

  __shared__ float sQ[36];
  __shared__ float sMB[32];
  __shared__ int   sIdx[32];        // clamped (for s_pts/s_lrf)
  __shared__ int   sIdxX[32];       // unclamped (xh has zero row at NSn)
  __shared__ float sZ[32];
  __shared__ float sNbr[32][3];
  __shared__ alignas(16) _Float16 sLrfA[32][72];    // [h][sbc], 144B rows
  __shared__ alignas(16) _Float16 sBw2[4][32][72];  // [q][m][sbc]
  __shared__ alignas(16) _Float16 sWb[4][16][40];   // [q][k][h]
  __shared__ alignas(16) _Float16 sFt[4][32][40];   // [q][m][h]

  // ---- phase 1: prelim loads + zero pads ----
  if (tid < 36) sQ[tid]  = q_lrf[(size_t)n*36 + tid];
  if (tid < 32) sMB[tid] = mlp_b[tid];
  if (tid < 32) {
    int idx = nbi[(size_t)n*Hh + tid];
    int sh = (idx >= NSn) ? 1 : 0;
    sZ[tid]    = sh ? 0.f : 1.f;
    sIdx[tid]  = sh ? 0 : idx;
    sIdxX[tid] = idx;              // idx in [0, NSn]; row NSn of xh is zero
  }
  { unsigned* z = (unsigned*)&sBw2[0][0][0];
    for (int i = tid; i < 4608; i += 256) z[i] = 0u; }
  { unsigned* z = (unsigned*)&sLrfA[0][0];
    for (int i = tid; i < 1152; i += 256) z[i] = 0u; }
  __syncthreads();

  // ---- phase 2: gathers + W2 ----
  if (tid < 96) {
    int h = tid / 3, d = tid - h*3;
    sNbr[h][d] = sZ[h] * s_pts[(size_t)sIdx[h]*3 + d] - q_pts[(size_t)n*3 + d];
  }
  // s_lrf gather, float4-vectorized: 288 float4 (row = f4i/9, c4 = f4i%9)
  for (int f4i = tid; f4i < 288; f4i += 256) {
    int row = f4i / 9, c4 = f4i - row*9;
    float4 v = *reinterpret_cast<const float4*>(
        s_lrf + (size_t)sIdx[row]*36 + c4*4);
    float z = sZ[row];
    uint2 pk;
    pk.x = pack2h(z*v.x, z*v.y);
    pk.y = pack2h(z*v.z, z*v.w);
    *reinterpret_cast<uint2*>(&sLrfA[row][c4*4]) = pk;
  }
  // W2: 4608 outputs, 18 per thread [r6 verbatim]
  #pragma unroll
  for (int it = 0; it < 18; ++it) {
    int i = tid + it*256;
    int q = i / 1152, r = i - q*1152;
    int k = r >> 5, m = r & 31;
    int s = k / 9, bc = k - s*9, b = bc / 3, c = bc - b*3;
    int br = (s*9 + c)*32 + m;
    float acc = sQ[q*9 + b*3 + 0] * mlp_w[br]
              + sQ[q*9 + b*3 + 1] * mlp_w[br + 96]
              + sQ[q*9 + b*3 + 2] * mlp_w[br + 192];
    sBw2[q][m][k] = (_Float16)acc;
  }
  __syncthreads();

  // ---- phase 3: influence weights + feat MFMA [r6 verbatim] ----
  {
    int h = lane & 31, kh = lane >> 5;
    float a0 = 0.f, a1 = 0.f, a2 = 0.f;
    #pragma unroll
    for (int d = 0; d < 3; ++d) {
      float nd = sNbr[h][d];
      a0 += nd * sQ[wv*9 + d*3 + 0];
      a1 += nd * sQ[wv*9 + d*3 + 1];
      a2 += nd * sQ[wv*9 + d*3 + 2];
    }
    float z = sZ[h];
    int k0 = kh * 8, kend = kh ? 15 : 8;
    for (int k = k0; k < kend; ++k) {
      float d0 = a0 - kp[k*3+0];
      float d1 = a1 - kp[k*3+1];
      float d2 = a2 - kp[k*3+2];
      float wgt = 1.f - sqrtf(d0*d0 + d1*d1 + d2*d2) * (1.0f/1.2f);
      sWb[wv][k][h] = (_Float16)(z * fmaxf(wgt, 0.f));
    }
    if (kh) sWb[wv][15][h] = (_Float16)0.f;
  }
  { // feat: [32h x 64k] @ [64k x 32m], K padded with zeros
    f32x4 fa[2][2];
    #pragma unroll
    for (int i = 0; i < 2; ++i)
      #pragma unroll
      for (int j = 0; j < 2; ++j) fa[i][j] = (f32x4){0.f,0.f,0.f,0.f};
    #pragma unroll
    for (int kc = 0; kc < 2; ++kc) {
      f16x8 af0 = *reinterpret_cast<const f16x8*>(&sLrfA[l15][kc*32 + lg*8]);
      f16x8 af1 = *reinterpret_cast<const f16x8*>(&sLrfA[16 + l15][kc*32 + lg*8]);
      f16x8 bf0 = *reinterpret_cast<const f16x8*>(&sBw2[wv][l15][kc*32 + lg*8]);
      f16x8 bf1 = *reinterpret_cast<const f16x8*>(&sBw2[wv][16 + l15][kc*32 + lg*8]);
      fa[0][0] = __builtin_amdgcn_mfma_f32_16x16x32_f16(af0, bf0, fa[0][0], 0, 0, 0);
      fa[0][1] = __builtin_amdgcn_mfma_f32_16x16x32_f16(af0, bf1, fa[0][1], 0, 0, 0);
      fa[1][0] = __builtin_amdgcn_mfma_f32_16x16x32_f16(af1, bf0, fa[1][0], 0, 0, 0);
      fa[1][1] = __builtin_amdgcn_mfma_f32_16x16x32_f16(af1, bf1, fa[1][1], 0, 0, 0);
    }
    // epilogue: +bias (masked via z), write transposed [m][h] as uint2
    #pragma unroll
    for (int ht = 0; ht < 2; ++ht) {
      int hb = ht*16 + lg*4;
      float z0 = sZ[hb+0], z1 = sZ[hb+1], z2 = sZ[hb+2], z3 = sZ[hb+3];
      #pragma unroll
      for (int mt = 0; mt < 2; ++mt) {
        int m = mt*16 + l15;
        float bias = sMB[m];
        uint2 pk;
        pk.x = pack2h(fmaf(z0, bias, fa[ht][mt][0]), fmaf(z1, bias, fa[ht][mt][1]));
        pk.y = pack2h(fmaf(z2, bias, fa[ht][mt][2]), fmaf(z3, bias, fa[ht][mt][3]));
        *reinterpret_cast<uint2*>(&sFt[wv][m][hb]) = pk;
      }
    }
  }
  __syncthreads();

  // ---- phase 4: aggregation MFMA + padded k-major store ----
  {
    f16x8 a = *reinterpret_cast<const f16x8*>(&sWb[wv][l15][lg*8]);
    // x-half B-frags from xh; shadow neighbors read the zero row (no masks)
    union { unsigned u[4]; f16x8 v; } B0, B1;
    #pragma unroll
    for (int j = 0; j < 8; j += 2) {
      int h0 = lg*8 + j, h1 = h0 + 1;
      size_t r0 = (size_t)sIdxX[h0]*128 + wv*32 + l15;
      size_t r1 = (size_t)sIdxX[h1]*128 + wv*32 + l15;
      B0.u[j >> 1] = (unsigned)xh[r0]      | ((unsigned)xh[r1]      << 16);
      B1.u[j >> 1] = (unsigned)xh[r0 + 16] | ((unsigned)xh[r1 + 16] << 16);
    }
    f16x8 b2 = *reinterpret_cast<const f16x8*>(&sFt[wv][l15][lg*8]);
    f16x8 b3 = *reinterpret_cast<const f16x8*>(&sFt[wv][16 + l15][lg*8]);

    // wf[n][col*16 + k], col = wv*64 + ni*16 + l15, k = lg*4 + v.
    // k=15 slot = MFMA row 15 = 0 (sWb row 15 zeroed); wt pad is also 0.
    _Float16* wp = wf_out + (size_t)n*FDIMP + ((wv*64 + l15) << 4) + (lg << 2);
    f32x4 acc;  uint2 pk;
    acc = (f32x4){0.f,0.f,0.f,0.f};
    acc = __builtin_amdgcn_mfma_f32_16x16x32_f16(a, B0.v, acc, 0, 0, 0);
    pk.x = pack2h(acc[0], acc[1]); pk.y = pack2h(acc[2], acc[3]);
    *reinterpret_cast<uint2*>(wp) = pk;
    acc = (f32x4){0.f,0.f,0.f,0.f};
    acc = __builtin_amdgcn_mfma_f32_16x16x32_f16(a, B1.v, acc, 0, 0, 0);
    pk.x = pack2h(acc[0], acc[1]); pk.y = pack2h(acc[2], acc[3]);
    *reinterpret_cast<uint2*>(wp + 256) = pk;
    acc = (f32x4){0.f,0.f,0.f,0.f};
    acc = __builtin_amdgcn_mfma_f32_16x16x32_f16(a, b2, acc, 0, 0, 0);
    pk.x = pack2h(acc[0], acc[1]); pk.y = pack2h(acc[2], acc[3]);
    *reinterpret_cast<uint2*>(wp + 512) = pk;
    acc = (f32x4){0.f,0.f,0.f,0.f};
    acc = __builtin_amdgcn_mfma_f32_16x16x32_f16(a, b3, acc, 0, 0, 0);
    pk.x = pack2h(acc[0], acc[1]); pk.y = pack2h(acc[2], acc[3]);
    *reinterpret_cast<uint2*>(wp + 768) = pk;
  }
}

// ---------------------------------------------------------------------------
// Stage 2: out = wf @ W over the padded f' dim (4096). BM=32, BN=128, grid 313.
// ---------------------------------------------------------------------------
__global__ __launch_bounds__(256, 4) void ekp_gemm4(
    const _Float16* __restrict__ A,   // [M][FDIMP]
    const _Float16* __restrict__ Bt,  // [128][FDIMP]
    float* __restrict__ C)
{
  __shared__ alignas(16) _Float16 As[32][72];
  __shared__ alignas(16) _Float16 Bs[128][72];
  const int tid = threadIdx.x, lane = tid & 63, w = tid >> 6;
  const int wr = w >> 1, wc = w & 1;
  const int r0 = blockIdx.x * 32;
  const int l15 = lane & 15, lg = lane >> 4;

  f32x4 acc[4];
  #pragma unroll
  for (int i = 0; i < 4; ++i) acc[i] = (f32x4){0.f,0.f,0.f,0.f};

  const int sr = tid >> 3;          // 0..31
  const int ak = (tid & 7) << 3;    // 0..56
  const _Float16* ap = A  + (size_t)(r0 + sr)*FDIMP + ak;
  const _Float16* bp = Bt + (size_t)sr*FDIMP + ak;

  for (int kc = 0; kc < FDIMP; kc += 64) {
    *reinterpret_cast<f16x8*>(&As[sr][ak]) = *reinterpret_cast<const f16x8*>(ap + kc);
    #pragma unroll
    for (int p = 0; p < 4; ++p)
      *reinterpret_cast<f16x8*>(&Bs[p*32 + sr][ak]) =
        *reinterpret_cast<const f16x8*>(bp + (size_t)p*32*FDIMP + kc);
    __syncthreads();
    #pragma unroll
    for (int k2 = 0; k2 < 2; ++k2) {
      const int ko = k2*32 + lg*8;
      f16x8 a = *reinterpret_cast<const f16x8*>(&As[wr*16 + l15][ko]);
      #pragma unroll
      for (int ni = 0; ni < 4; ++ni) {
        f16x8 b = *reinterpret_cast<const f16x8*>(&Bs[wc*64 + ni*16 + l15][ko]);
        acc[ni] = __builtin_amdgcn_mfma_f32_16x16x32_f16(a, b, acc[ni], 0, 0, 0);
      }
    }
    __syncthreads();
  }
  #pragma unroll
  for (int v = 0; v < 4; ++v) {
    int gr = r0 + wr*16 + lg*4 + v;
    if (gr < NQn) {
      #pragma unroll
      for (int ni = 0; ni < 4; ++ni)
        C[(size_t)gr*128 + wc*64 + ni*16 + l15] = acc[ni][v];
    }
  }
}

// ---------------------------------------------------------------------------
// Fallback (ws too small): round-1 fused f32 kernel — known-correct.
// ---------------------------------------------------------------------------
__global__ __launch_bounds__(256) void ekp_stage1_fused(
    const float* __restrict__ q_pts, const float* __restrict__ s_pts,
    const int*   __restrict__ nbi,   const float* __restrict__ x,
    const float* __restrict__ q_lrf, const float* __restrict__ s_lrf,
    const float* __restrict__ weights, const float* __restrict__ kp,
    const float* __restrict__ mlp_w, const float* __restrict__ mlp_b,
    float* __restrict__ out)
{
  const int n = blockIdx.x;
  const int tid = threadIdx.x;

  __shared__ float sQ[36];
  __shared__ float sKP[45];
  __shared__ float sMW[36][32];
  __shared__ float sMB[32];
  __shared__ int   sIdx[32];
  __shared__ int   sShad[32];
  __shared__ float sNbr[32][3];
  __shared__ float sLrf[32][37];
  __shared__ float sW[4][15][32];
  __shared__ float sNbx[32][4][65];

  if (tid < 36) sQ[tid]  = q_lrf[(size_t)n*36 + tid];
  if (tid < 45) sKP[tid] = kp[tid];
  if (tid < 32) sMB[tid] = mlp_b[tid];
  for (int i = tid; i < 36*32; i += 256) sMW[i >> 5][i & 31] = mlp_w[i];
  if (tid < 32) {
    int idx = nbi[(size_t)n*Hh + tid];
    int sh = (idx >= NSn) ? 1 : 0;
    sShad[tid] = sh;
    sIdx[tid]  = sh ? 0 : idx;
  }
  __syncthreads();

  if (tid < 96) {
    int h = tid / 3, d = tid - h*3;
    float v = sShad[h] ? 0.f : s_pts[(size_t)sIdx[h]*3 + d];
    sNbr[h][d] = v - q_pts[(size_t)n*3 + d];
  }
  {
    int h = tid >> 3, j0 = tid & 7;
    const float* src = s_lrf + (size_t)sIdx[h]*36;
    float z = sShad[h] ? 0.f : 1.f;
    for (int j = j0; j < 36; j += 8) sLrf[h][j] = z * src[j];
  }
  for (int i = tid; i < Hh*128; i += 256) {
    int h = i >> 7, c = i & 127;
    float v = sShad[h] ? 0.f : x[(size_t)sIdx[h]*128 + c];
    sNbx[h][c >> 5][c & 31] = v;
  }
  __syncthreads();

  {
    int q = tid >> 6, l = tid & 63;
    int h = l & 31, kh = l >> 5;
    float a0 = 0.f, a1 = 0.f, a2 = 0.f;
    #pragma unroll
    for (int d = 0; d < 3; ++d) {
      float nd = sNbr[h][d];
      a0 += nd * sQ[q*9 + d*3 + 0];
      a1 += nd * sQ[q*9 + d*3 + 1];
      a2 += nd * sQ[q*9 + d*3 + 2];
    }
    float z = sShad[h] ? 0.f : 1.f;
    int k0 = kh * 8;
    int kend = k0 + (kh ? 7 : 8);
    for (int k = k0; k < kend; ++k) {
      float d0 = a0 - sKP[k*3+0];
      float d1 = a1 - sKP[k*3+1];
      float d2 = a2 - sKP[k*3+2];
      float wv2 = 1.f - sqrtf(d0*d0 + d1*d1 + d2*d2) * (1.0f/1.2f);
      sW[q][k][h] = z * fmaxf(wv2, 0.f);
    }
  }
  {
    int q = tid >> 6, l = tid & 63;
    int h = l & 31, mh = l >> 5;
    float fi[36];
    #pragma unroll
    for (int s = 0; s < 4; ++s)
      #pragma unroll
      for (int a = 0; a < 3; ++a)
        #pragma unroll
        for (int c = 0; c < 3; ++c) {
          float accv = 0.f;
          #pragma unroll
          for (int b = 0; b < 3; ++b)
            accv += sQ[q*9 + b*3 + a] * sLrf[h][s*9 + b*3 + c];
          fi[s*9 + a*3 + c] = accv;
        }
    float z = sShad[h] ? 0.f : 1.f;
    int m0 = mh * 16;
    for (int mm = 0; mm < 16; ++mm) {
      int m = m0 + mm;
      float accv = sMB[m];
      #pragma unroll
      for (int j = 0; j < 36; ++j) accv += fi[j] * sMW[j][m];
      sNbx[h][q][32 + m] = z * accv;
    }
  }
  __syncthreads();

  float acc[15];
  const int q = tid >> 6, cch = tid & 63;
  #pragma unroll
  for (int k = 0; k < 15; ++k) acc[k] = 0.f;
  for (int h = 0; h < Hh; ++h) {
    float v = sNbx[h][q][cch];
    #pragma unroll
    for (int k = 0; k < 15; ++k) acc[k] += sW[q][k][h] * v;
  }

  __shared__ float sWF[FDIM];
  __shared__ float sRed[2][128];
  #pragma unroll
  for (int k = 0; k < 15; ++k) sWF[k*256 + q*64 + cch] = acc[k];
  __syncthreads();
  int o = tid & 127, part = tid >> 7;
  const float* wp = weights + (size_t)part*1920*128 + o;
  const float* wfp = sWF + part*1920;
  float oa = 0.f;
  #pragma unroll 8
  for (int f = 0; f < 1920; ++f)
    oa += wfp[f] * wp[(size_t)f*128];
  sRed[part][o] = oa;
  __syncthreads();
  if (tid < 128) out[(size_t)n*128 + tid] = sRed[0][tid] + sRed[1][tid];
}

extern "C" void kernel_launch(void* const* d_in, const int* in_sizes, int n_in,
                              void* d_out, int out_size, void* d_ws, size_t ws_size,
                              hipStream_t stream) {
  const float* q_pts   = (const float*)d_in[0];
  const float* s_pts   = (const float*)d_in[1];
  const int*   nbi     = (const int*)  d_in[2];
  const float* x       = (const float*)d_in[3];
  const float* q_lrf   = (const float*)d_in[4];
  const float* s_lrf   = (const float*)d_in[5];
  const float* weights = (const float*)d_in[6];
  const float* kp      = (const float*)d_in[7];
  const float* mlp_w   = (const float*)d_in[8];
  const float* mlp_b   = (const float*)d_in[9];
  float* out = (float*)d_out;

  const size_t nWf = (size_t)NQn * FDIMP;
  const size_t nWt = (size_t)128 * FDIMP;
  const size_t nXh = (size_t)(NSn + 1) * 128;   // +1 zero row for shadows
  const size_t needBytes = (nWf + nWt + nXh) * sizeof(_Float16);
  if (ws_size >= needBytes) {
    _Float16* wf = (_Float16*)d_ws;
    _Float16* wt = wf + nWf;
    _Float16* xh = wt + nWt;
    ekp_prep6<<<1138, 256, 0, stream>>>(weights, x, wt, xh);
    ekp_stage1i<<<NQn, 256, 0, stream>>>(q_pts, s_pts, nbi,
                                         (const unsigned short*)xh,
                                         q_lrf, s_lrf, kp, mlp_w, mlp_b, wf);
    ekp_gemm4<<<(NQn + 31)/32, 256, 0, stream>>>(wf, wt, out);
  } else {
    ekp_stage1_fused<<<NQn, 256, 0, stream>>>(q_pts, s_pts, nbi, x, q_lrf, s_lrf,
                                              weights, kp, mlp_w, mlp_b, out);
  }
}

// Round 11
// 133.146 us; speedup vs baseline: 1.0978x; 1.0978x over previous
//
#include <hip/hip_runtime.h>

#define NQn 10000
#define NSn 10000
#define Hh  32
#define FDIM 3840   // K(15) * 2*IN_CH(256)

typedef _Float16 f16x8 __attribute__((ext_vector_type(8)));
typedef float    f32x4 __attribute__((ext_vector_type(4)));

__device__ __forceinline__ unsigned pack2h(float a, float b) {
  union { _Float16 h; unsigned short u; } ua, ub;
  ua.h = (_Float16)a; ub.h = (_Float16)b;
  return (unsigned)ua.u | ((unsigned)ub.u << 16);
}

// ---------------------------------------------------------------------------
// Prep (1106 blocks) [r9 verbatim]:
//   b <  625 : xh[i] = fp16(x[i])               (10000x128, vectorized)
//   b == 625 : xh row NSn = 0                   (shadow zero-row)
//   else     : wt[n][k] = fp16(weights[k][n])   (LDS tile transpose)
// ---------------------------------------------------------------------------
__global__ __launch_bounds__(256) void ekp_prep5(
    const float* __restrict__ w, const float* __restrict__ x,
    _Float16* __restrict__ wt, _Float16* __restrict__ xh)
{
  const int b = blockIdx.x, tid = threadIdx.x;
  if (b < 625) {
    size_t base = (size_t)b*2048 + (size_t)tid*8;
    float4 a0 = *reinterpret_cast<const float4*>(x + base);
    float4 a1 = *reinterpret_cast<const float4*>(x + base + 4);
    uint4 o;
    o.x = pack2h(a0.x, a0.y); o.y = pack2h(a0.z, a0.w);
    o.z = pack2h(a1.x, a1.y); o.w = pack2h(a1.z, a1.w);
    *reinterpret_cast<uint4*>(xh + base) = o;
  } else if (b == 625) {
    if (tid < 64)
      reinterpret_cast<unsigned*>(xh + (size_t)NSn*128)[tid] = 0u;
  } else {
    __shared__ _Float16 t[32][34];
    const int tt = b - 626;
    const int k0 = (tt % 120) * 32, n0 = (tt / 120) * 32;
    const int c = tid & 31, r0 = tid >> 5;
    #pragma unroll
    for (int p = 0; p < 4; ++p) {
      int r = r0 + p*8;
      t[c][r] = (_Float16)w[(size_t)(k0 + r)*128 + n0 + c];
    }
    __syncthreads();
    #pragma unroll
    for (int p = 0; p < 4; ++p) {
      int r = r0 + p*8;
      wt[(size_t)(n0 + r)*FDIM + k0 + c] = t[r][c];
    }
  }
}

// ---------------------------------------------------------------------------
// Stage 1j: r9's verified stage1h with ONE delta: sFt is aliased into the
// dead sBw2 region (wave-private from P3 on; epilogue writes are data-
// dependent on the MFMA reads, so no ordering hazard). LDS 39.9 -> 29.2 KB
// => 5 blocks/CU.
// ---------------------------------------------------------------------------
__global__ __launch_bounds__(256, 5) void ekp_stage1j(
    const float* __restrict__ q_pts, const float* __restrict__ s_pts,
    const int*   __restrict__ nbi,   const unsigned short* __restrict__ xh,
    const float* __restrict__ q_lrf, const float* __restrict__ s_lrf,
    const float* __restrict__ kp,    const float* __restrict__ mlp_w,
    const float* __restrict__ mlp_b, _Float16* __restrict__ wf_out)
{
  const int n = blockIdx.x;
  const int tid = threadIdx.x;
  const int lane = tid & 63;
  const int wv = tid >> 6;          // wave id == q
  const int l15 = lane & 15, lg = lane >> 4;

  __shared__ float sQ[36];
  __shared__ float sMB[32];
  __shared__ int   sIdx[32];        // clamped (for s_pts/s_lrf)
  __shared__ int   sIdxX[32];       // unclamped (xh has zero row at NSn)
  __shared__ float sZ[32];
  __shared__ float sNbr[32][3];
  __shared__ alignas(16) _Float16 sLrfA[32][72];    // [h][sbc], 144B rows
  __shared__ alignas(16) _Float16 sBw2[4][32][72];  // [q][m][sbc]; after the
                                                    // feat MFMA, row (q,m)
                                                    // is reused as sFt[q][m]
  __shared__ alignas(16) _Float16 sWb[4][16][40];   // [q][k][h]
  #define sFtP(q, m) (&sBw2[q][m][0])               // aliased feat row [h]

  // ---- phase 1: prelim loads + zero pads [r9 verbatim] ----
  if (tid < 36) sQ[tid]  = q_lrf[(size_t)n*36 + tid];
  if (tid < 32) sMB[tid] = mlp_b[tid];
  if (tid < 32) {
    int idx = nbi[(size_t)n*Hh + tid];
    int sh = (idx >= NSn) ? 1 : 0;
    sZ[tid]    = sh ? 0.f : 1.f;
    sIdx[tid]  = sh ? 0 : idx;
    sIdxX[tid] = idx;              // idx in [0, NSn]; row NSn of xh is zero
  }
  { unsigned* z = (unsigned*)&sBw2[0][0][0];
    for (int i = tid; i < 4608; i += 256) z[i] = 0u; }
  { unsigned* z = (unsigned*)&sLrfA[0][0];
    for (int i = tid; i < 1152; i += 256) z[i] = 0u; }
  __syncthreads();

  // ---- phase 2: gathers + W2 [r9 verbatim] ----
  if (tid < 96) {
    int h = tid / 3, d = tid - h*3;
    sNbr[h][d] = sZ[h] * s_pts[(size_t)sIdx[h]*3 + d] - q_pts[(size_t)n*3 + d];
  }
  // s_lrf gather, float4-vectorized: 288 float4 (row = f4i/9, c4 = f4i%9)
  for (int f4i = tid; f4i < 288; f4i += 256) {
    int row = f4i / 9, c4 = f4i - row*9;
    float4 v = *reinterpret_cast<const float4*>(
        s_lrf + (size_t)sIdx[row]*36 + c4*4);
    float z = sZ[row];
    uint2 pk;
    pk.x = pack2h(z*v.x, z*v.y);
    pk.y = pack2h(z*v.z, z*v.w);
    *reinterpret_cast<uint2*>(&sLrfA[row][c4*4]) = pk;
  }
  // W2: 4608 outputs, 18 per thread
  #pragma unroll
  for (int it = 0; it < 18; ++it) {
    int i = tid + it*256;
    int q = i / 1152, r = i - q*1152;
    int k = r >> 5, m = r & 31;
    int s = k / 9, bc = k - s*9, b = bc / 3, c = bc - b*3;
    int br = (s*9 + c)*32 + m;
    float acc = sQ[q*9 + b*3 + 0] * mlp_w[br]
              + sQ[q*9 + b*3 + 1] * mlp_w[br + 96]
              + sQ[q*9 + b*3 + 2] * mlp_w[br + 192];
    sBw2[q][m][k] = (_Float16)acc;
  }
  __syncthreads();

  // ---- phase 3: influence weights + feat MFMA ----
  {
    int h = lane & 31, kh = lane >> 5;
    float a0 = 0.f, a1 = 0.f, a2 = 0.f;
    #pragma unroll
    for (int d = 0; d < 3; ++d) {
      float nd = sNbr[h][d];
      a0 += nd * sQ[wv*9 + d*3 + 0];
      a1 += nd * sQ[wv*9 + d*3 + 1];
      a2 += nd * sQ[wv*9 + d*3 + 2];
    }
    float z = sZ[h];
    int k0 = kh * 8, kend = kh ? 15 : 8;
    for (int k = k0; k < kend; ++k) {
      float d0 = a0 - kp[k*3+0];
      float d1 = a1 - kp[k*3+1];
      float d2 = a2 - kp[k*3+2];
      float wgt = 1.f - sqrtf(d0*d0 + d1*d1 + d2*d2) * (1.0f/1.2f);
      sWb[wv][k][h] = (_Float16)(z * fmaxf(wgt, 0.f));
    }
    if (kh) sWb[wv][15][h] = (_Float16)0.f;
  }
  { // feat: [32h x 64k] @ [64k x 32m], K padded with zeros
    f32x4 fa[2][2];
    #pragma unroll
    for (int i = 0; i < 2; ++i)
      #pragma unroll
      for (int j = 0; j < 2; ++j) fa[i][j] = (f32x4){0.f,0.f,0.f,0.f};
    #pragma unroll
    for (int kc = 0; kc < 2; ++kc) {
      f16x8 af0 = *reinterpret_cast<const f16x8*>(&sLrfA[l15][kc*32 + lg*8]);
      f16x8 af1 = *reinterpret_cast<const f16x8*>(&sLrfA[16 + l15][kc*32 + lg*8]);
      f16x8 bf0 = *reinterpret_cast<const f16x8*>(&sBw2[wv][l15][kc*32 + lg*8]);
      f16x8 bf1 = *reinterpret_cast<const f16x8*>(&sBw2[wv][16 + l15][kc*32 + lg*8]);
      fa[0][0] = __builtin_amdgcn_mfma_f32_16x16x32_f16(af0, bf0, fa[0][0], 0, 0, 0);
      fa[0][1] = __builtin_amdgcn_mfma_f32_16x16x32_f16(af0, bf1, fa[0][1], 0, 0, 0);
      fa[1][0] = __builtin_amdgcn_mfma_f32_16x16x32_f16(af1, bf0, fa[1][0], 0, 0, 0);
      fa[1][1] = __builtin_amdgcn_mfma_f32_16x16x32_f16(af1, bf1, fa[1][1], 0, 0, 0);
    }
    // epilogue: +bias (masked via z); write [m][h] into the aliased sBw2[wv]
    // rows (dead after the MFMAs above — register dep orders read-then-write)
    #pragma unroll
    for (int ht = 0; ht < 2; ++ht) {
      int hb = ht*16 + lg*4;
      float z0 = sZ[hb+0], z1 = sZ[hb+1], z2 = sZ[hb+2], z3 = sZ[hb+3];
      #pragma unroll
      for (int mt = 0; mt < 2; ++mt) {
        int m = mt*16 + l15;
        float bias = sMB[m];
        uint2 pk;
        pk.x = pack2h(fmaf(z0, bias, fa[ht][mt][0]), fmaf(z1, bias, fa[ht][mt][1]));
        pk.y = pack2h(fmaf(z2, bias, fa[ht][mt][2]), fmaf(z3, bias, fa[ht][mt][3]));
        *reinterpret_cast<uint2*>(sFtP(wv, m) + hb) = pk;
      }
    }
  }
  __syncthreads();

  // ---- phase 4: aggregation MFMA + global store [r9 structure] ----
  {
    f16x8 a = *reinterpret_cast<const f16x8*>(&sWb[wv][l15][lg*8]);
    // x-half B-frags from xh; shadow neighbors read the zero row (no masks)
    union { unsigned u[4]; f16x8 v; } B0, B1;
    #pragma unroll
    for (int j = 0; j < 8; j += 2) {
      int h0 = lg*8 + j, h1 = h0 + 1;
      size_t r0 = (size_t)sIdxX[h0]*128 + wv*32 + l15;
      size_t r1 = (size_t)sIdxX[h1]*128 + wv*32 + l15;
      B0.u[j >> 1] = (unsigned)xh[r0]      | ((unsigned)xh[r1]      << 16);
      B1.u[j >> 1] = (unsigned)xh[r0 + 16] | ((unsigned)xh[r1 + 16] << 16);
    }
    f16x8 b2 = *reinterpret_cast<const f16x8*>(sFtP(wv, l15) + lg*8);
    f16x8 b3 = *reinterpret_cast<const f16x8*>(sFtP(wv, 16 + l15) + lg*8);

    _Float16* wp = wf_out + (size_t)n*FDIM + wv*64 + l15;
    f32x4 acc;
    acc = (f32x4){0.f,0.f,0.f,0.f};
    acc = __builtin_amdgcn_mfma_f32_16x16x32_f16(a, B0.v, acc, 0, 0, 0);
    #pragma unroll
    for (int v = 0; v < 4; ++v) { int k = lg*4 + v; if (k < 15) wp[k*256 +  0] = (_Float16)acc[v]; }
    acc = (f32x4){0.f,0.f,0.f,0.f};
    acc = __builtin_amdgcn_mfma_f32_16x16x32_f16(a, B1.v, acc, 0, 0, 0);
    #pragma unroll
    for (int v = 0; v < 4; ++v) { int k = lg*4 + v; if (k < 15) wp[k*256 + 16] = (_Float16)acc[v]; }
    acc = (f32x4){0.f,0.f,0.f,0.f};
    acc = __builtin_amdgcn_mfma_f32_16x16x32_f16(a, b2, acc, 0, 0, 0);
    #pragma unroll
    for (int v = 0; v < 4; ++v) { int k = lg*4 + v; if (k < 15) wp[k*256 + 32] = (_Float16)acc[v]; }
    acc = (f32x4){0.f,0.f,0.f,0.f};
    acc = __builtin_amdgcn_mfma_f32_16x16x32_f16(a, b3, acc, 0, 0, 0);
    #pragma unroll
    for (int v = 0; v < 4; ++v) { int k = lg*4 + v; if (k < 15) wp[k*256 + 48] = (_Float16)acc[v]; }
  }
  #undef sFtP
}

// ---------------------------------------------------------------------------
// Stage 2 [verified, r9 verbatim]: out = wf @ W. BM=32, BN=128, grid 313.
// ---------------------------------------------------------------------------
__global__ __launch_bounds__(256, 4) void ekp_gemm3(
    const _Float16* __restrict__ A,   // [M][FDIM]
    const _Float16* __restrict__ Bt,  // [128][FDIM]
    float* __restrict__ C)
{
  __shared__ alignas(16) _Float16 As[32][72];
  __shared__ alignas(16) _Float16 Bs[128][72];
  const int tid = threadIdx.x, lane = tid & 63, w = tid >> 6;
  const int wr = w >> 1, wc = w & 1;
  const int r0 = blockIdx.x * 32;
  const int l15 = lane & 15, lg = lane >> 4;

  f32x4 acc[4];
  #pragma unroll
  for (int i = 0; i < 4; ++i) acc[i] = (f32x4){0.f,0.f,0.f,0.f};

  const int sr = tid >> 3;          // 0..31
  const int ak = (tid & 7) << 3;    // 0..56
  const _Float16* ap = A  + (size_t)(r0 + sr)*FDIM + ak;
  const _Float16* bp = Bt + (size_t)sr*FDIM + ak;

  for (int kc = 0; kc < FDIM; kc += 64) {
    *reinterpret_cast<f16x8*>(&As[sr][ak]) = *reinterpret_cast<const f16x8*>(ap + kc);
    #pragma unroll
    for (int p = 0; p < 4; ++p)
      *reinterpret_cast<f16x8*>(&Bs[p*32 + sr][ak]) =
        *reinterpret_cast<const f16x8*>(bp + (size_t)p*32*FDIM + kc);
    __syncthreads();
    #pragma unroll
    for (int k2 = 0; k2 < 2; ++k2) {
      const int ko = k2*32 + lg*8;
      f16x8 a = *reinterpret_cast<const f16x8*>(&As[wr*16 + l15][ko]);
      #pragma unroll
      for (int ni = 0; ni < 4; ++ni) {
        f16x8 b = *reinterpret_cast<const f16x8*>(&Bs[wc*64 + ni*16 + l15][ko]);
        acc[ni] = __builtin_amdgcn_mfma_f32_16x16x32_f16(a, b, acc[ni], 0, 0, 0);
      }
    }
    __syncthreads();
  }
  #pragma unroll
  for (int v = 0; v < 4; ++v) {
    int gr = r0 + wr*16 + lg*4 + v;
    if (gr < NQn) {
      #pragma unroll
      for (int ni = 0; ni < 4; ++ni)
        C[(size_t)gr*128 + wc*64 + ni*16 + l15] = acc[ni][v];
    }
  }
}

// ---------------------------------------------------------------------------
// Fallback (ws too small): round-1 fused f32 kernel — known-correct.
// ---------------------------------------------------------------------------
__global__ __launch_bounds__(256) void ekp_stage1_fused(
    const float* __restrict__ q_pts, const float* __restrict__ s_pts,
    const int*   __restrict__ nbi,   const float* __restrict__ x,
    const float* __restrict__ q_lrf, const float* __restrict__ s_lrf,
    const float* __restrict__ weights, const float* __restrict__ kp,
    const float* __restrict__ mlp_w, const float* __restrict__ mlp_b,
    float* __restrict__ out)
{
  const int n = blockIdx.x;
  const int tid = threadIdx.x;

  __shared__ float sQ[36];
  __shared__ float sKP[45];
  __shared__ float sMW[36][32];
  __shared__ float sMB[32];
  __shared__ int   sIdx[32];
  __shared__ int   sShad[32];
  __shared__ float sNbr[32][3];
  __shared__ float sLrf[32][37];
  __shared__ float sW[4][15][32];
  __shared__ float sNbx[32][4][65];

  if (tid < 36) sQ[tid]  = q_lrf[(size_t)n*36 + tid];
  if (tid < 45) sKP[tid] = kp[tid];
  if (tid < 32) sMB[tid] = mlp_b[tid];
  for (int i = tid; i < 36*32; i += 256) sMW[i >> 5][i & 31] = mlp_w[i];
  if (tid < 32) {
    int idx = nbi[(size_t)n*Hh + tid];
    int sh = (idx >= NSn) ? 1 : 0;
    sShad[tid] = sh;
    sIdx[tid]  = sh ? 0 : idx;
  }
  __syncthreads();

  if (tid < 96) {
    int h = tid / 3, d = tid - h*3;
    float v = sShad[h] ? 0.f : s_pts[(size_t)sIdx[h]*3 + d];
    sNbr[h][d] = v - q_pts[(size_t)n*3 + d];
  }
  {
    int h = tid >> 3, j0 = tid & 7;
    const float* src = s_lrf + (size_t)sIdx[h]*36;
    float z = sShad[h] ? 0.f : 1.f;
    for (int j = j0; j < 36; j += 8) sLrf[h][j] = z * src[j];
  }
  for (int i = tid; i < Hh*128; i += 256) {
    int h = i >> 7, c = i & 127;
    float v = sShad[h] ? 0.f : x[(size_t)sIdx[h]*128 + c];
    sNbx[h][c >> 5][c & 31] = v;
  }
  __syncthreads();

  {
    int q = tid >> 6, l = tid & 63;
    int h = l & 31, kh = l >> 5;
    float a0 = 0.f, a1 = 0.f, a2 = 0.f;
    #pragma unroll
    for (int d = 0; d < 3; ++d) {
      float nd = sNbr[h][d];
      a0 += nd * sQ[q*9 + d*3 + 0];
      a1 += nd * sQ[q*9 + d*3 + 1];
      a2 += nd * sQ[q*9 + d*3 + 2];
    }
    float z = sShad[h] ? 0.f : 1.f;
    int k0 = kh * 8;
    int kend = k0 + (kh ? 7 : 8);
    for (int k = k0; k < kend; ++k) {
      float d0 = a0 - sKP[k*3+0];
      float d1 = a1 - sKP[k*3+1];
      float d2 = a2 - sKP[k*3+2];
      float wv2 = 1.f - sqrtf(d0*d0 + d1*d1 + d2*d2) * (1.0f/1.2f);
      sW[q][k][h] = z * fmaxf(wv2, 0.f);
    }
  }
  {
    int q = tid >> 6, l = tid & 63;
    int h = l & 31, mh = l >> 5;
    float fi[36];
    #pragma unroll
    for (int s = 0; s < 4; ++s)
      #pragma unroll
      for (int a = 0; a < 3; ++a)
        #pragma unroll
        for (int c = 0; c < 3; ++c) {
          float accv = 0.f;
          #pragma unroll
          for (int b = 0; b < 3; ++b)
            accv += sQ[q*9 + b*3 + a] * sLrf[h][s*9 + b*3 + c];
          fi[s*9 + a*3 + c] = accv;
        }
    float z = sShad[h] ? 0.f : 1.f;
    int m0 = mh * 16;
    for (int mm = 0; mm < 16; ++mm) {
      int m = m0 + mm;
      float accv = sMB[m];
      #pragma unroll
      for (int j = 0; j < 36; ++j) accv += fi[j] * sMW[j][m];
      sNbx[h][q][32 + m] = z * accv;
    }
  }
  __syncthreads();

  float acc[15];
  const int q = tid >> 6, cch = tid & 63;
  #pragma unroll
  for (int k = 0; k < 15; ++k) acc[k] = 0.f;
  for (int h = 0; h < Hh; ++h) {
    float v = sNbx[h][q][cch];
    #pragma unroll
    for (int k = 0; k < 15; ++k) acc[k] += sW[q][k][h] * v;
  }

  __shared__ float sWF[FDIM];
  __shared__ float sRed[2][128];
  #pragma unroll
  for (int k = 0; k < 15; ++k) sWF[k*256 + q*64 + cch] = acc[k];
  __syncthreads();
  int o = tid & 127, part = tid >> 7;
  const float* wp = weights + (size_t)part*1920*128 + o;
  const float* wfp = sWF + part*1920;
  float oa = 0.f;
  #pragma unroll 8
  for (int f = 0; f < 1920; ++f)
    oa += wfp[f] * wp[(size_t)f*128];
  sRed[part][o] = oa;
  __syncthreads();
  if (tid < 128) out[(size_t)n*128 + tid] = sRed[0][tid] + sRed[1][tid];
}

extern "C" void kernel_launch(void* const* d_in, const int* in_sizes, int n_in,
                              void* d_out, int out_size, void* d_ws, size_t ws_size,
                              hipStream_t stream) {
  const float* q_pts   = (const float*)d_in[0];
  const float* s_pts   = (const float*)d_in[1];
  const int*   nbi     = (const int*)  d_in[2];
  const float* x       = (const float*)d_in[3];
  const float* q_lrf   = (const float*)d_in[4];
  const float* s_lrf   = (const float*)d_in[5];
  const float* weights = (const float*)d_in[6];
  const float* kp      = (const float*)d_in[7];
  const float* mlp_w   = (const float*)d_in[8];
  const float* mlp_b   = (const float*)d_in[9];
  float* out = (float*)d_out;

  const size_t nWf = (size_t)NQn * FDIM;
  const size_t nWt = (size_t)128 * FDIM;
  const size_t nXh = (size_t)(NSn + 1) * 128;   // +1 zero row for shadows
  const size_t needBytes = (nWf + nWt + nXh) * sizeof(_Float16);
  if (ws_size >= needBytes) {
    _Float16* wf = (_Float16*)d_ws;
    _Float16* wt = wf + nWf;
    _Float16* xh = wt + nWt;
    ekp_prep5<<<1106, 256, 0, stream>>>(weights, x, wt, xh);
    ekp_stage1j<<<NQn, 256, 0, stream>>>(q_pts, s_pts, nbi,
                                         (const unsigned short*)xh,
                                         q_lrf, s_lrf, kp, mlp_w, mlp_b, wf);
    ekp_gemm3<<<(NQn + 31)/32, 256, 0, stream>>>(wf, wt, out);
  } else {
    ekp_stage1_fused<<<NQn, 256, 0, stream>>>(q_pts, s_pts, nbi, x, q_lrf, s_lrf,
                                              weights, kp, mlp_w, mlp_b, out);
  }
}

// Round 12
// 119.978 us; speedup vs baseline: 1.2183x; 1.1098x over previous
//
#include <hip/hip_runtime.h>

#define NQn 10000
#define NSn 10000
#define Hh  32
#define FDIM 3840    // K(15) * 2*IN_CH(256)
#define KSPLIT 4
#define KCHUNK (FDIM / KSPLIT)   // 960 = 15 iters of 64

typedef _Float16 f16x8 __attribute__((ext_vector_type(8)));
typedef float    f32x4 __attribute__((ext_vector_type(4)));

__device__ __forceinline__ unsigned pack2h(float a, float b) {
  union { _Float16 h; unsigned short u; } ua, ub;
  ua.h = (_Float16)a; ub.h = (_Float16)b;
  return (unsigned)ua.u | ((unsigned)ub.u << 16);
}

// ---------------------------------------------------------------------------
// Prep (1106 blocks) [r11 verbatim]:
//   b <  625 : xh[i] = fp16(x[i])               (10000x128, vectorized)
//   b == 625 : xh row NSn = 0                   (shadow zero-row)
//   else     : wt[n][k] = fp16(weights[k][n])   (LDS tile transpose)
// ---------------------------------------------------------------------------
__global__ __launch_bounds__(256) void ekp_prep5(
    const float* __restrict__ w, const float* __restrict__ x,
    _Float16* __restrict__ wt, _Float16* __restrict__ xh)
{
  const int b = blockIdx.x, tid = threadIdx.x;
  if (b < 625) {
    size_t base = (size_t)b*2048 + (size_t)tid*8;
    float4 a0 = *reinterpret_cast<const float4*>(x + base);
    float4 a1 = *reinterpret_cast<const float4*>(x + base + 4);
    uint4 o;
    o.x = pack2h(a0.x, a0.y); o.y = pack2h(a0.z, a0.w);
    o.z = pack2h(a1.x, a1.y); o.w = pack2h(a1.z, a1.w);
    *reinterpret_cast<uint4*>(xh + base) = o;
  } else if (b == 625) {
    if (tid < 64)
      reinterpret_cast<unsigned*>(xh + (size_t)NSn*128)[tid] = 0u;
  } else {
    __shared__ _Float16 t[32][34];
    const int tt = b - 626;
    const int k0 = (tt % 120) * 32, n0 = (tt / 120) * 32;
    const int c = tid & 31, r0 = tid >> 5;
    #pragma unroll
    for (int p = 0; p < 4; ++p) {
      int r = r0 + p*8;
      t[c][r] = (_Float16)w[(size_t)(k0 + r)*128 + n0 + c];
    }
    __syncthreads();
    #pragma unroll
    for (int p = 0; p < 4; ++p) {
      int r = r0 + p*8;
      wt[(size_t)(n0 + r)*FDIM + k0 + c] = t[r][c];
    }
  }
}

// ---------------------------------------------------------------------------
// Stage 1j [r11 verbatim, verified]: sFt aliased into dead sBw2 region;
// LDS 29.2 KB => 5 blocks/CU.
// ---------------------------------------------------------------------------
__global__ __launch_bounds__(256, 5) void ekp_stage1j(
    const float* __restrict__ q_pts, const float* __restrict__ s_pts,
    const int*   __restrict__ nbi,   const unsigned short* __restrict__ xh,
    const float* __restrict__ q_lrf, const float* __restrict__ s_lrf,
    const float* __restrict__ kp,    const float* __restrict__ mlp_w,
    const float* __restrict__ mlp_b, _Float16* __restrict__ wf_out)
{
  const int n = blockIdx.x;
  const int tid = threadIdx.x;
  const int lane = tid & 63;
  const int wv = tid >> 6;          // wave id == q
  const int l15 = lane & 15, lg = lane >> 4;

  __shared__ float sQ[36];
  __shared__ float sMB[32];
  __shared__ int   sIdx[32];        // clamped (for s_pts/s_lrf)
  __shared__ int   sIdxX[32];       // unclamped (xh has zero row at NSn)
  __shared__ float sZ[32];
  __shared__ float sNbr[32][3];
  __shared__ alignas(16) _Float16 sLrfA[32][72];    // [h][sbc], 144B rows
  __shared__ alignas(16) _Float16 sBw2[4][32][72];  // [q][m][sbc]; aliased as
                                                    // sFt[q][m] after feat MFMA
  __shared__ alignas(16) _Float16 sWb[4][16][40];   // [q][k][h]
  #define sFtP(q, m) (&sBw2[q][m][0])               // aliased feat row [h]

  // ---- phase 1 ----
  if (tid < 36) sQ[tid]  = q_lrf[(size_t)n*36 + tid];
  if (tid < 32) sMB[tid] = mlp_b[tid];
  if (tid < 32) {
    int idx = nbi[(size_t)n*Hh + tid];
    int sh = (idx >= NSn) ? 1 : 0;
    sZ[tid]    = sh ? 0.f : 1.f;
    sIdx[tid]  = sh ? 0 : idx;
    sIdxX[tid] = idx;              // idx in [0, NSn]; row NSn of xh is zero
  }
  { unsigned* z = (unsigned*)&sBw2[0][0][0];
    for (int i = tid; i < 4608; i += 256) z[i] = 0u; }
  { unsigned* z = (unsigned*)&sLrfA[0][0];
    for (int i = tid; i < 1152; i += 256) z[i] = 0u; }
  __syncthreads();

  // ---- phase 2: gathers + W2 ----
  if (tid < 96) {
    int h = tid / 3, d = tid - h*3;
    sNbr[h][d] = sZ[h] * s_pts[(size_t)sIdx[h]*3 + d] - q_pts[(size_t)n*3 + d];
  }
  for (int f4i = tid; f4i < 288; f4i += 256) {
    int row = f4i / 9, c4 = f4i - row*9;
    float4 v = *reinterpret_cast<const float4*>(
        s_lrf + (size_t)sIdx[row]*36 + c4*4);
    float z = sZ[row];
    uint2 pk;
    pk.x = pack2h(z*v.x, z*v.y);
    pk.y = pack2h(z*v.z, z*v.w);
    *reinterpret_cast<uint2*>(&sLrfA[row][c4*4]) = pk;
  }
  #pragma unroll
  for (int it = 0; it < 18; ++it) {
    int i = tid + it*256;
    int q = i / 1152, r = i - q*1152;
    int k = r >> 5, m = r & 31;
    int s = k / 9, bc = k - s*9, b = bc / 3, c = bc - b*3;
    int br = (s*9 + c)*32 + m;
    float acc = sQ[q*9 + b*3 + 0] * mlp_w[br]
              + sQ[q*9 + b*3 + 1] * mlp_w[br + 96]
              + sQ[q*9 + b*3 + 2] * mlp_w[br + 192];
    sBw2[q][m][k] = (_Float16)acc;
  }
  __syncthreads();

  // ---- phase 3: influence weights + feat MFMA ----
  {
    int h = lane & 31, kh = lane >> 5;
    float a0 = 0.f, a1 = 0.f, a2 = 0.f;
    #pragma unroll
    for (int d = 0; d < 3; ++d) {
      float nd = sNbr[h][d];
      a0 += nd * sQ[wv*9 + d*3 + 0];
      a1 += nd * sQ[wv*9 + d*3 + 1];
      a2 += nd * sQ[wv*9 + d*3 + 2];
    }
    float z = sZ[h];
    int k0 = kh * 8, kend = kh ? 15 : 8;
    for (int k = k0; k < kend; ++k) {
      float d0 = a0 - kp[k*3+0];
      float d1 = a1 - kp[k*3+1];
      float d2 = a2 - kp[k*3+2];
      float wgt = 1.f - sqrtf(d0*d0 + d1*d1 + d2*d2) * (1.0f/1.2f);
      sWb[wv][k][h] = (_Float16)(z * fmaxf(wgt, 0.f));
    }
    if (kh) sWb[wv][15][h] = (_Float16)0.f;
  }
  {
    f32x4 fa[2][2];
    #pragma unroll
    for (int i = 0; i < 2; ++i)
      #pragma unroll
      for (int j = 0; j < 2; ++j) fa[i][j] = (f32x4){0.f,0.f,0.f,0.f};
    #pragma unroll
    for (int kc = 0; kc < 2; ++kc) {
      f16x8 af0 = *reinterpret_cast<const f16x8*>(&sLrfA[l15][kc*32 + lg*8]);
      f16x8 af1 = *reinterpret_cast<const f16x8*>(&sLrfA[16 + l15][kc*32 + lg*8]);
      f16x8 bf0 = *reinterpret_cast<const f16x8*>(&sBw2[wv][l15][kc*32 + lg*8]);
      f16x8 bf1 = *reinterpret_cast<const f16x8*>(&sBw2[wv][16 + l15][kc*32 + lg*8]);
      fa[0][0] = __builtin_amdgcn_mfma_f32_16x16x32_f16(af0, bf0, fa[0][0], 0, 0, 0);
      fa[0][1] = __builtin_amdgcn_mfma_f32_16x16x32_f16(af0, bf1, fa[0][1], 0, 0, 0);
      fa[1][0] = __builtin_amdgcn_mfma_f32_16x16x32_f16(af1, bf0, fa[1][0], 0, 0, 0);
      fa[1][1] = __builtin_amdgcn_mfma_f32_16x16x32_f16(af1, bf1, fa[1][1], 0, 0, 0);
    }
    #pragma unroll
    for (int ht = 0; ht < 2; ++ht) {
      int hb = ht*16 + lg*4;
      float z0 = sZ[hb+0], z1 = sZ[hb+1], z2 = sZ[hb+2], z3 = sZ[hb+3];
      #pragma unroll
      for (int mt = 0; mt < 2; ++mt) {
        int m = mt*16 + l15;
        float bias = sMB[m];
        uint2 pk;
        pk.x = pack2h(fmaf(z0, bias, fa[ht][mt][0]), fmaf(z1, bias, fa[ht][mt][1]));
        pk.y = pack2h(fmaf(z2, bias, fa[ht][mt][2]), fmaf(z3, bias, fa[ht][mt][3]));
        *reinterpret_cast<uint2*>(sFtP(wv, m) + hb) = pk;
      }
    }
  }
  __syncthreads();

  // ---- phase 4: aggregation MFMA + global store ----
  {
    f16x8 a = *reinterpret_cast<const f16x8*>(&sWb[wv][l15][lg*8]);
    union { unsigned u[4]; f16x8 v; } B0, B1;
    #pragma unroll
    for (int j = 0; j < 8; j += 2) {
      int h0 = lg*8 + j, h1 = h0 + 1;
      size_t r0 = (size_t)sIdxX[h0]*128 + wv*32 + l15;
      size_t r1 = (size_t)sIdxX[h1]*128 + wv*32 + l15;
      B0.u[j >> 1] = (unsigned)xh[r0]      | ((unsigned)xh[r1]      << 16);
      B1.u[j >> 1] = (unsigned)xh[r0 + 16] | ((unsigned)xh[r1 + 16] << 16);
    }
    f16x8 b2 = *reinterpret_cast<const f16x8*>(sFtP(wv, l15) + lg*8);
    f16x8 b3 = *reinterpret_cast<const f16x8*>(sFtP(wv, 16 + l15) + lg*8);

    _Float16* wp = wf_out + (size_t)n*FDIM + wv*64 + l15;
    f32x4 acc;
    acc = (f32x4){0.f,0.f,0.f,0.f};
    acc = __builtin_amdgcn_mfma_f32_16x16x32_f16(a, B0.v, acc, 0, 0, 0);
    #pragma unroll
    for (int v = 0; v < 4; ++v) { int k = lg*4 + v; if (k < 15) wp[k*256 +  0] = (_Float16)acc[v]; }
    acc = (f32x4){0.f,0.f,0.f,0.f};
    acc = __builtin_amdgcn_mfma_f32_16x16x32_f16(a, B1.v, acc, 0, 0, 0);
    #pragma unroll
    for (int v = 0; v < 4; ++v) { int k = lg*4 + v; if (k < 15) wp[k*256 + 16] = (_Float16)acc[v]; }
    acc = (f32x4){0.f,0.f,0.f,0.f};
    acc = __builtin_amdgcn_mfma_f32_16x16x32_f16(a, b2, acc, 0, 0, 0);
    #pragma unroll
    for (int v = 0; v < 4; ++v) { int k = lg*4 + v; if (k < 15) wp[k*256 + 32] = (_Float16)acc[v]; }
    acc = (f32x4){0.f,0.f,0.f,0.f};
    acc = __builtin_amdgcn_mfma_f32_16x16x32_f16(a, b3, acc, 0, 0, 0);
    #pragma unroll
    for (int v = 0; v < 4; ++v) { int k = lg*4 + v; if (k < 15) wp[k*256 + 48] = (_Float16)acc[v]; }
  }
  #undef sFtP
}

// ---------------------------------------------------------------------------
// Stage 2, split-K: Cpart[kz] = wf[:, kz*960:(kz+1)*960] @ W-chunk.
// Grid (313, 4). Inner loop = verified gemm3 body with kbase offset.
// ---------------------------------------------------------------------------
__global__ __launch_bounds__(256, 4) void ekp_gemm5(
    const _Float16* __restrict__ A,   // [M][FDIM]
    const _Float16* __restrict__ Bt,  // [128][FDIM]
    float* __restrict__ Cpart)        // [KSPLIT][M][128]
{
  __shared__ alignas(16) _Float16 As[32][72];
  __shared__ alignas(16) _Float16 Bs[128][72];
  const int tid = threadIdx.x, lane = tid & 63, w = tid >> 6;
  const int wr = w >> 1, wc = w & 1;
  const int r0 = blockIdx.x * 32;
  const int kbase = blockIdx.y * KCHUNK;
  const int l15 = lane & 15, lg = lane >> 4;

  f32x4 acc[4];
  #pragma unroll
  for (int i = 0; i < 4; ++i) acc[i] = (f32x4){0.f,0.f,0.f,0.f};

  const int sr = tid >> 3;          // 0..31
  const int ak = (tid & 7) << 3;    // 0..56
  const _Float16* ap = A  + (size_t)(r0 + sr)*FDIM + ak;
  const _Float16* bp = Bt + (size_t)sr*FDIM + ak;

  for (int kc = kbase; kc < kbase + KCHUNK; kc += 64) {
    *reinterpret_cast<f16x8*>(&As[sr][ak]) = *reinterpret_cast<const f16x8*>(ap + kc);
    #pragma unroll
    for (int p = 0; p < 4; ++p)
      *reinterpret_cast<f16x8*>(&Bs[p*32 + sr][ak]) =
        *reinterpret_cast<const f16x8*>(bp + (size_t)p*32*FDIM + kc);
    __syncthreads();
    #pragma unroll
    for (int k2 = 0; k2 < 2; ++k2) {
      const int ko = k2*32 + lg*8;
      f16x8 a = *reinterpret_cast<const f16x8*>(&As[wr*16 + l15][ko]);
      #pragma unroll
      for (int ni = 0; ni < 4; ++ni) {
        f16x8 b = *reinterpret_cast<const f16x8*>(&Bs[wc*64 + ni*16 + l15][ko]);
        acc[ni] = __builtin_amdgcn_mfma_f32_16x16x32_f16(a, b, acc[ni], 0, 0, 0);
      }
    }
    __syncthreads();
  }
  float* C = Cpart + (size_t)blockIdx.y * NQn * 128;
  #pragma unroll
  for (int v = 0; v < 4; ++v) {
    int gr = r0 + wr*16 + lg*4 + v;
    if (gr < NQn) {
      #pragma unroll
      for (int ni = 0; ni < 4; ++ni)
        C[(size_t)gr*128 + wc*64 + ni*16 + l15] = acc[ni][v];
    }
  }
}

// ---------------------------------------------------------------------------
// Reduce: out = sum of 4 partials. 1250 blocks x 256 threads x float4 (exact).
// ---------------------------------------------------------------------------
__global__ __launch_bounds__(256) void ekp_reduce(
    const float* __restrict__ P, float* __restrict__ out)
{
  const size_t i = (size_t)blockIdx.x * 256 + threadIdx.x;   // < 320000
  const size_t stride = (size_t)NQn * 128 / 4;               // float4 stride
  const float4* p = reinterpret_cast<const float4*>(P);
  float4 a = p[i], b = p[i + stride], c = p[i + 2*stride], d = p[i + 3*stride];
  float4 r;
  r.x = (a.x + b.x) + (c.x + d.x);
  r.y = (a.y + b.y) + (c.y + d.y);
  r.z = (a.z + b.z) + (c.z + d.z);
  r.w = (a.w + b.w) + (c.w + d.w);
  reinterpret_cast<float4*>(out)[i] = r;
}

// ---------------------------------------------------------------------------
// Fallback (ws too small): round-1 fused f32 kernel — known-correct.
// ---------------------------------------------------------------------------
__global__ __launch_bounds__(256) void ekp_stage1_fused(
    const float* __restrict__ q_pts, const float* __restrict__ s_pts,
    const int*   __restrict__ nbi,   const float* __restrict__ x,
    const float* __restrict__ q_lrf, const float* __restrict__ s_lrf,
    const float* __restrict__ weights, const float* __restrict__ kp,
    const float* __restrict__ mlp_w, const float* __restrict__ mlp_b,
    float* __restrict__ out)
{
  const int n = blockIdx.x;
  const int tid = threadIdx.x;

  __shared__ float sQ[36];
  __shared__ float sKP[45];
  __shared__ float sMW[36][32];
  __shared__ float sMB[32];
  __shared__ int   sIdx[32];
  __shared__ int   sShad[32];
  __shared__ float sNbr[32][3];
  __shared__ float sLrf[32][37];
  __shared__ float sW[4][15][32];
  __shared__ float sNbx[32][4][65];

  if (tid < 36) sQ[tid]  = q_lrf[(size_t)n*36 + tid];
  if (tid < 45) sKP[tid] = kp[tid];
  if (tid < 32) sMB[tid] = mlp_b[tid];
  for (int i = tid; i < 36*32; i += 256) sMW[i >> 5][i & 31] = mlp_w[i];
  if (tid < 32) {
    int idx = nbi[(size_t)n*Hh + tid];
    int sh = (idx >= NSn) ? 1 : 0;
    sShad[tid] = sh;
    sIdx[tid]  = sh ? 0 : idx;
  }
  __syncthreads();

  if (tid < 96) {
    int h = tid / 3, d = tid - h*3;
    float v = sShad[h] ? 0.f : s_pts[(size_t)sIdx[h]*3 + d];
    sNbr[h][d] = v - q_pts[(size_t)n*3 + d];
  }
  {
    int h = tid >> 3, j0 = tid & 7;
    const float* src = s_lrf + (size_t)sIdx[h]*36;
    float z = sShad[h] ? 0.f : 1.f;
    for (int j = j0; j < 36; j += 8) sLrf[h][j] = z * src[j];
  }
  for (int i = tid; i < Hh*128; i += 256) {
    int h = i >> 7, c = i & 127;
    float v = sShad[h] ? 0.f : x[(size_t)sIdx[h]*128 + c];
    sNbx[h][c >> 5][c & 31] = v;
  }
  __syncthreads();

  {
    int q = tid >> 6, l = tid & 63;
    int h = l & 31, kh = l >> 5;
    float a0 = 0.f, a1 = 0.f, a2 = 0.f;
    #pragma unroll
    for (int d = 0; d < 3; ++d) {
      float nd = sNbr[h][d];
      a0 += nd * sQ[q*9 + d*3 + 0];
      a1 += nd * sQ[q*9 + d*3 + 1];
      a2 += nd * sQ[q*9 + d*3 + 2];
    }
    float z = sShad[h] ? 0.f : 1.f;
    int k0 = kh * 8;
    int kend = k0 + (kh ? 7 : 8);
    for (int k = k0; k < kend; ++k) {
      float d0 = a0 - sKP[k*3+0];
      float d1 = a1 - sKP[k*3+1];
      float d2 = a2 - sKP[k*3+2];
      float wv2 = 1.f - sqrtf(d0*d0 + d1*d1 + d2*d2) * (1.0f/1.2f);
      sW[q][k][h] = z * fmaxf(wv2, 0.f);
    }
  }
  {
    int q = tid >> 6, l = tid & 63;
    int h = l & 31, mh = l >> 5;
    float fi[36];
    #pragma unroll
    for (int s = 0; s < 4; ++s)
      #pragma unroll
      for (int a = 0; a < 3; ++a)
        #pragma unroll
        for (int c = 0; c < 3; ++c) {
          float accv = 0.f;
          #pragma unroll
          for (int b = 0; b < 3; ++b)
            accv += sQ[q*9 + b*3 + a] * sLrf[h][s*9 + b*3 + c];
          fi[s*9 + a*3 + c] = accv;
        }
    float z = sShad[h] ? 0.f : 1.f;
    int m0 = mh * 16;
    for (int mm = 0; mm < 16; ++mm) {
      int m = m0 + mm;
      float accv = sMB[m];
      #pragma unroll
      for (int j = 0; j < 36; ++j) accv += fi[j] * sMW[j][m];
      sNbx[h][q][32 + m] = z * accv;
    }
  }
  __syncthreads();

  float acc[15];
  const int q = tid >> 6, cch = tid & 63;
  #pragma unroll
  for (int k = 0; k < 15; ++k) acc[k] = 0.f;
  for (int h = 0; h < Hh; ++h) {
    float v = sNbx[h][q][cch];
    #pragma unroll
    for (int k = 0; k < 15; ++k) acc[k] += sW[q][k][h] * v;
  }

  __shared__ float sWF[FDIM];
  __shared__ float sRed[2][128];
  #pragma unroll
  for (int k = 0; k < 15; ++k) sWF[k*256 + q*64 + cch] = acc[k];
  __syncthreads();
  int o = tid & 127, part = tid >> 7;
  const float* wp = weights + (size_t)part*1920*128 + o;
  const float* wfp = sWF + part*1920;
  float oa = 0.f;
  #pragma unroll 8
  for (int f = 0; f < 1920; ++f)
    oa += wfp[f] * wp[(size_t)f*128];
  sRed[part][o] = oa;
  __syncthreads();
  if (tid < 128) out[(size_t)n*128 + tid] = sRed[0][tid] + sRed[1][tid];
}

extern "C" void kernel_launch(void* const* d_in, const int* in_sizes, int n_in,
                              void* d_out, int out_size, void* d_ws, size_t ws_size,
                              hipStream_t stream) {
  const float* q_pts   = (const float*)d_in[0];
  const float* s_pts   = (const float*)d_in[1];
  const int*   nbi     = (const int*)  d_in[2];
  const float* x       = (const float*)d_in[3];
  const float* q_lrf   = (const float*)d_in[4];
  const float* s_lrf   = (const float*)d_in[5];
  const float* weights = (const float*)d_in[6];
  const float* kp      = (const float*)d_in[7];
  const float* mlp_w   = (const float*)d_in[8];
  const float* mlp_b   = (const float*)d_in[9];
  float* out = (float*)d_out;

  const size_t nWf = (size_t)NQn * FDIM;              // fp16 elems
  const size_t nWt = (size_t)128 * FDIM;
  const size_t nXh = (size_t)(NSn + 1) * 128;
  const size_t h16 = nWf + nWt + nXh;                 // fp16 count (even)
  const size_t needBytes = h16 * sizeof(_Float16)
                         + (size_t)KSPLIT * NQn * 128 * sizeof(float);
  if (ws_size >= needBytes) {
    _Float16* wf = (_Float16*)d_ws;
    _Float16* wt = wf + nWf;
    _Float16* xh = wt + nWt;
    float* cpart = (float*)(xh + nXh);                // 16B-aligned (h16*2 % 16 == 0)
    ekp_prep5<<<1106, 256, 0, stream>>>(weights, x, wt, xh);
    ekp_stage1j<<<NQn, 256, 0, stream>>>(q_pts, s_pts, nbi,
                                         (const unsigned short*)xh,
                                         q_lrf, s_lrf, kp, mlp_w, mlp_b, wf);
    dim3 gg((NQn + 31)/32, KSPLIT);
    ekp_gemm5<<<gg, 256, 0, stream>>>(wf, wt, cpart);
    ekp_reduce<<<NQn*128/(256*4), 256, 0, stream>>>(cpart, out);
  } else {
    ekp_stage1_fused<<<NQn, 256, 0, stream>>>(q_pts, s_pts, nbi, x, q_lrf, s_lrf,
                                              weights, kp, mlp_w, mlp_b, out);
  }
}

// Round 13
// 118.055 us; speedup vs baseline: 1.2381x; 1.0163x over previous
//
#include <hip/hip_runtime.h>

#define NQn 10000
#define NSn 10000
#define Hh  32
#define FDIM 3840    // K(15) * 2*IN_CH(256)
#define KSPLIT 4
#define KCHUNK (FDIM / KSPLIT)   // 960 = 15 iters of 64

typedef _Float16 f16x8 __attribute__((ext_vector_type(8)));
typedef float    f32x4 __attribute__((ext_vector_type(4)));

__device__ __forceinline__ unsigned pack2h(float a, float b) {
  union { _Float16 h; unsigned short u; } ua, ub;
  ua.h = (_Float16)a; ub.h = (_Float16)b;
  return (unsigned)ua.u | ((unsigned)ub.u << 16);
}

// ---------------------------------------------------------------------------
// Prep (1146 blocks):
//   b <  625 : xh[i] = fp16(x[i])                 (10000x128)
//   b == 625 : zero xh row NSn + zero slh row NSn (shadow rows)
//   b < 1106 : wt[n][k] = fp16(weights[k][n])     (LDS tile transpose)
//   else     : slh[r][j] = j<36 ? fp16(s_lrf[r][j]) : 0   (rows of 64)
// ---------------------------------------------------------------------------
__global__ __launch_bounds__(256) void ekp_prep8(
    const float* __restrict__ w, const float* __restrict__ x,
    const float* __restrict__ s_lrf,
    _Float16* __restrict__ wt, _Float16* __restrict__ xh,
    _Float16* __restrict__ slh)
{
  const int b = blockIdx.x, tid = threadIdx.x;
  if (b < 625) {
    size_t base = (size_t)b*2048 + (size_t)tid*8;
    float4 a0 = *reinterpret_cast<const float4*>(x + base);
    float4 a1 = *reinterpret_cast<const float4*>(x + base + 4);
    uint4 o;
    o.x = pack2h(a0.x, a0.y); o.y = pack2h(a0.z, a0.w);
    o.z = pack2h(a1.x, a1.y); o.w = pack2h(a1.z, a1.w);
    *reinterpret_cast<uint4*>(xh + base) = o;
  } else if (b == 625) {
    if (tid < 64)
      reinterpret_cast<unsigned*>(xh + (size_t)NSn*128)[tid] = 0u;
    else if (tid < 96)
      reinterpret_cast<unsigned*>(slh + (size_t)NSn*64)[tid - 64] = 0u;
  } else if (b < 1106) {
    __shared__ _Float16 t[32][34];
    const int tt = b - 626;
    const int k0 = (tt % 120) * 32, n0 = (tt / 120) * 32;
    const int c = tid & 31, r0 = tid >> 5;
    #pragma unroll
    for (int p = 0; p < 4; ++p) {
      int r = r0 + p*8;
      t[c][r] = (_Float16)w[(size_t)(k0 + r)*128 + n0 + c];
    }
    __syncthreads();
    #pragma unroll
    for (int p = 0; p < 4; ++p) {
      int r = r0 + p*8;
      wt[(size_t)(n0 + r)*FDIM + k0 + c] = t[r][c];
    }
  } else {
    int row = (b - 1106)*256 + tid;
    if (row < NSn) {
      const float* src = s_lrf + (size_t)row*36;
      float v[36];
      #pragma unroll
      for (int j = 0; j < 9; ++j)
        *reinterpret_cast<float4*>(&v[j*4]) =
            reinterpret_cast<const float4*>(src)[j];
      unsigned d[32];
      #pragma unroll
      for (int j = 0; j < 18; ++j) d[j] = pack2h(v[2*j], v[2*j+1]);
      #pragma unroll
      for (int j = 18; j < 32; ++j) d[j] = 0u;
      uint4* dst = reinterpret_cast<uint4*>(slh + (size_t)row*64);
      #pragma unroll
      for (int j = 0; j < 8; ++j)
        dst[j] = make_uint4(d[4*j], d[4*j+1], d[4*j+2], d[4*j+3]);
    }
  }
}

// ---------------------------------------------------------------------------
// Stage 1k: r12's verified stage1j with ONE delta: sLrfA removed from LDS;
// feat-MFMA A-frags read per-lane from the padded global slh table via
// sIdxX (proven xh pattern). LDS 29.7 -> 24.6 KB => 6 blocks/CU.
// ---------------------------------------------------------------------------
__global__ __launch_bounds__(256, 6) void ekp_stage1k(
    const float* __restrict__ q_pts, const float* __restrict__ s_pts,
    const int*   __restrict__ nbi,   const unsigned short* __restrict__ xh,
    const float* __restrict__ q_lrf, const _Float16* __restrict__ slh,
    const float* __restrict__ kp,    const float* __restrict__ mlp_w,
    const float* __restrict__ mlp_b, _Float16* __restrict__ wf_out)
{
  const int n = blockIdx.x;
  const int tid = threadIdx.x;
  const int lane = tid & 63;
  const int wv = tid >> 6;          // wave id == q
  const int l15 = lane & 15, lg = lane >> 4;

  __shared__ float sQ[36];
  __shared__ float sMB[32];
  __shared__ int   sIdx[32];        // clamped (for s_pts)
  __shared__ int   sIdxX[32];       // unclamped (xh/slh have zero row NSn)
  __shared__ float sZ[32];
  __shared__ float sNbr[32][3];
  __shared__ alignas(16) _Float16 sBw2[4][32][72];  // [q][m][sbc]; aliased as
                                                    // sFt[q][m] after feat MFMA
  __shared__ alignas(16) _Float16 sWb[4][16][40];   // [q][k][h]
  #define sFtP(q, m) (&sBw2[q][m][0])               // aliased feat row [h]

  // ---- phase 1 ----
  if (tid < 36) sQ[tid]  = q_lrf[(size_t)n*36 + tid];
  if (tid < 32) sMB[tid] = mlp_b[tid];
  if (tid < 32) {
    int idx = nbi[(size_t)n*Hh + tid];
    int sh = (idx >= NSn) ? 1 : 0;
    sZ[tid]    = sh ? 0.f : 1.f;
    sIdx[tid]  = sh ? 0 : idx;
    sIdxX[tid] = idx;              // idx in [0, NSn]; row NSn is zero
  }
  { unsigned* z = (unsigned*)&sBw2[0][0][0];
    for (int i = tid; i < 4608; i += 256) z[i] = 0u; }
  __syncthreads();

  // ---- phase 2: gathers + W2 [r12 verbatim] ----
  if (tid < 96) {
    int h = tid / 3, d = tid - h*3;
    sNbr[h][d] = sZ[h] * s_pts[(size_t)sIdx[h]*3 + d] - q_pts[(size_t)n*3 + d];
  }
  #pragma unroll
  for (int it = 0; it < 18; ++it) {
    int i = tid + it*256;
    int q = i / 1152, r = i - q*1152;
    int k = r >> 5, m = r & 31;
    int s = k / 9, bc = k - s*9, b = bc / 3, c = bc - b*3;
    int br = (s*9 + c)*32 + m;
    float acc = sQ[q*9 + b*3 + 0] * mlp_w[br]
              + sQ[q*9 + b*3 + 1] * mlp_w[br + 96]
              + sQ[q*9 + b*3 + 2] * mlp_w[br + 192];
    sBw2[q][m][k] = (_Float16)acc;
  }
  __syncthreads();

  // ---- phase 3: influence weights + feat MFMA ----
  {
    int h = lane & 31, kh = lane >> 5;
    float a0 = 0.f, a1 = 0.f, a2 = 0.f;
    #pragma unroll
    for (int d = 0; d < 3; ++d) {
      float nd = sNbr[h][d];
      a0 += nd * sQ[wv*9 + d*3 + 0];
      a1 += nd * sQ[wv*9 + d*3 + 1];
      a2 += nd * sQ[wv*9 + d*3 + 2];
    }
    float z = sZ[h];
    int k0 = kh * 8, kend = kh ? 15 : 8;
    for (int k = k0; k < kend; ++k) {
      float d0 = a0 - kp[k*3+0];
      float d1 = a1 - kp[k*3+1];
      float d2 = a2 - kp[k*3+2];
      float wgt = 1.f - sqrtf(d0*d0 + d1*d1 + d2*d2) * (1.0f/1.2f);
      sWb[wv][k][h] = (_Float16)(z * fmaxf(wgt, 0.f));
    }
    if (kh) sWb[wv][15][h] = (_Float16)0.f;
  }
  { // feat: A-frags from global slh (padded, zero row for shadows)
    const _Float16* a0p = slh + (size_t)sIdxX[l15]*64      + lg*8;
    const _Float16* a1p = slh + (size_t)sIdxX[16 + l15]*64 + lg*8;
    f32x4 fa[2][2];
    #pragma unroll
    for (int i = 0; i < 2; ++i)
      #pragma unroll
      for (int j = 0; j < 2; ++j) fa[i][j] = (f32x4){0.f,0.f,0.f,0.f};
    #pragma unroll
    for (int kc = 0; kc < 2; ++kc) {
      f16x8 af0 = *reinterpret_cast<const f16x8*>(a0p + kc*32);
      f16x8 af1 = *reinterpret_cast<const f16x8*>(a1p + kc*32);
      f16x8 bf0 = *reinterpret_cast<const f16x8*>(&sBw2[wv][l15][kc*32 + lg*8]);
      f16x8 bf1 = *reinterpret_cast<const f16x8*>(&sBw2[wv][16 + l15][kc*32 + lg*8]);
      fa[0][0] = __builtin_amdgcn_mfma_f32_16x16x32_f16(af0, bf0, fa[0][0], 0, 0, 0);
      fa[0][1] = __builtin_amdgcn_mfma_f32_16x16x32_f16(af0, bf1, fa[0][1], 0, 0, 0);
      fa[1][0] = __builtin_amdgcn_mfma_f32_16x16x32_f16(af1, bf0, fa[1][0], 0, 0, 0);
      fa[1][1] = __builtin_amdgcn_mfma_f32_16x16x32_f16(af1, bf1, fa[1][1], 0, 0, 0);
    }
    #pragma unroll
    for (int ht = 0; ht < 2; ++ht) {
      int hb = ht*16 + lg*4;
      float z0 = sZ[hb+0], z1 = sZ[hb+1], z2 = sZ[hb+2], z3 = sZ[hb+3];
      #pragma unroll
      for (int mt = 0; mt < 2; ++mt) {
        int m = mt*16 + l15;
        float bias = sMB[m];
        uint2 pk;
        pk.x = pack2h(fmaf(z0, bias, fa[ht][mt][0]), fmaf(z1, bias, fa[ht][mt][1]));
        pk.y = pack2h(fmaf(z2, bias, fa[ht][mt][2]), fmaf(z3, bias, fa[ht][mt][3]));
        *reinterpret_cast<uint2*>(sFtP(wv, m) + hb) = pk;
      }
    }
  }
  __syncthreads();

  // ---- phase 4: aggregation MFMA + global store [r12 verbatim] ----
  {
    f16x8 a = *reinterpret_cast<const f16x8*>(&sWb[wv][l15][lg*8]);
    union { unsigned u[4]; f16x8 v; } B0, B1;
    #pragma unroll
    for (int j = 0; j < 8; j += 2) {
      int h0 = lg*8 + j, h1 = h0 + 1;
      size_t r0 = (size_t)sIdxX[h0]*128 + wv*32 + l15;
      size_t r1 = (size_t)sIdxX[h1]*128 + wv*32 + l15;
      B0.u[j >> 1] = (unsigned)xh[r0]      | ((unsigned)xh[r1]      << 16);
      B1.u[j >> 1] = (unsigned)xh[r0 + 16] | ((unsigned)xh[r1 + 16] << 16);
    }
    f16x8 b2 = *reinterpret_cast<const f16x8*>(sFtP(wv, l15) + lg*8);
    f16x8 b3 = *reinterpret_cast<const f16x8*>(sFtP(wv, 16 + l15) + lg*8);

    _Float16* wp = wf_out + (size_t)n*FDIM + wv*64 + l15;
    f32x4 acc;
    acc = (f32x4){0.f,0.f,0.f,0.f};
    acc = __builtin_amdgcn_mfma_f32_16x16x32_f16(a, B0.v, acc, 0, 0, 0);
    #pragma unroll
    for (int v = 0; v < 4; ++v) { int k = lg*4 + v; if (k < 15) wp[k*256 +  0] = (_Float16)acc[v]; }
    acc = (f32x4){0.f,0.f,0.f,0.f};
    acc = __builtin_amdgcn_mfma_f32_16x16x32_f16(a, B1.v, acc, 0, 0, 0);
    #pragma unroll
    for (int v = 0; v < 4; ++v) { int k = lg*4 + v; if (k < 15) wp[k*256 + 16] = (_Float16)acc[v]; }
    acc = (f32x4){0.f,0.f,0.f,0.f};
    acc = __builtin_amdgcn_mfma_f32_16x16x32_f16(a, b2, acc, 0, 0, 0);
    #pragma unroll
    for (int v = 0; v < 4; ++v) { int k = lg*4 + v; if (k < 15) wp[k*256 + 32] = (_Float16)acc[v]; }
    acc = (f32x4){0.f,0.f,0.f,0.f};
    acc = __builtin_amdgcn_mfma_f32_16x16x32_f16(a, b3, acc, 0, 0, 0);
    #pragma unroll
    for (int v = 0; v < 4; ++v) { int k = lg*4 + v; if (k < 15) wp[k*256 + 48] = (_Float16)acc[v]; }
  }
  #undef sFtP
}

// ---------------------------------------------------------------------------
// Stage 2, split-K [r12 verbatim]: grid (313, 4).
// ---------------------------------------------------------------------------
__global__ __launch_bounds__(256, 4) void ekp_gemm5(
    const _Float16* __restrict__ A,   // [M][FDIM]
    const _Float16* __restrict__ Bt,  // [128][FDIM]
    float* __restrict__ Cpart)        // [KSPLIT][M][128]
{
  __shared__ alignas(16) _Float16 As[32][72];
  __shared__ alignas(16) _Float16 Bs[128][72];
  const int tid = threadIdx.x, lane = tid & 63, w = tid >> 6;
  const int wr = w >> 1, wc = w & 1;
  const int r0 = blockIdx.x * 32;
  const int kbase = blockIdx.y * KCHUNK;
  const int l15 = lane & 15, lg = lane >> 4;

  f32x4 acc[4];
  #pragma unroll
  for (int i = 0; i < 4; ++i) acc[i] = (f32x4){0.f,0.f,0.f,0.f};

  const int sr = tid >> 3;          // 0..31
  const int ak = (tid & 7) << 3;    // 0..56
  const _Float16* ap = A  + (size_t)(r0 + sr)*FDIM + ak;
  const _Float16* bp = Bt + (size_t)sr*FDIM + ak;

  for (int kc = kbase; kc < kbase + KCHUNK; kc += 64) {
    *reinterpret_cast<f16x8*>(&As[sr][ak]) = *reinterpret_cast<const f16x8*>(ap + kc);
    #pragma unroll
    for (int p = 0; p < 4; ++p)
      *reinterpret_cast<f16x8*>(&Bs[p*32 + sr][ak]) =
        *reinterpret_cast<const f16x8*>(bp + (size_t)p*32*FDIM + kc);
    __syncthreads();
    #pragma unroll
    for (int k2 = 0; k2 < 2; ++k2) {
      const int ko = k2*32 + lg*8;
      f16x8 a = *reinterpret_cast<const f16x8*>(&As[wr*16 + l15][ko]);
      #pragma unroll
      for (int ni = 0; ni < 4; ++ni) {
        f16x8 b = *reinterpret_cast<const f16x8*>(&Bs[wc*64 + ni*16 + l15][ko]);
        acc[ni] = __builtin_amdgcn_mfma_f32_16x16x32_f16(a, b, acc[ni], 0, 0, 0);
      }
    }
    __syncthreads();
  }
  float* C = Cpart + (size_t)blockIdx.y * NQn * 128;
  #pragma unroll
  for (int v = 0; v < 4; ++v) {
    int gr = r0 + wr*16 + lg*4 + v;
    if (gr < NQn) {
      #pragma unroll
      for (int ni = 0; ni < 4; ++ni)
        C[(size_t)gr*128 + wc*64 + ni*16 + l15] = acc[ni][v];
    }
  }
}

// ---------------------------------------------------------------------------
// Reduce [r12 verbatim]: out = sum of 4 partials.
// ---------------------------------------------------------------------------
__global__ __launch_bounds__(256) void ekp_reduce(
    const float* __restrict__ P, float* __restrict__ out)
{
  const size_t i = (size_t)blockIdx.x * 256 + threadIdx.x;
  const size_t stride = (size_t)NQn * 128 / 4;
  const float4* p = reinterpret_cast<const float4*>(P);
  float4 a = p[i], b = p[i + stride], c = p[i + 2*stride], d = p[i + 3*stride];
  float4 r;
  r.x = (a.x + b.x) + (c.x + d.x);
  r.y = (a.y + b.y) + (c.y + d.y);
  r.z = (a.z + b.z) + (c.z + d.z);
  r.w = (a.w + b.w) + (c.w + d.w);
  reinterpret_cast<float4*>(out)[i] = r;
}

// ---------------------------------------------------------------------------
// Fallback (ws too small): round-1 fused f32 kernel — known-correct.
// ---------------------------------------------------------------------------
__global__ __launch_bounds__(256) void ekp_stage1_fused(
    const float* __restrict__ q_pts, const float* __restrict__ s_pts,
    const int*   __restrict__ nbi,   const float* __restrict__ x,
    const float* __restrict__ q_lrf, const float* __restrict__ s_lrf,
    const float* __restrict__ weights, const float* __restrict__ kp,
    const float* __restrict__ mlp_w, const float* __restrict__ mlp_b,
    float* __restrict__ out)
{
  const int n = blockIdx.x;
  const int tid = threadIdx.x;

  __shared__ float sQ[36];
  __shared__ float sKP[45];
  __shared__ float sMW[36][32];
  __shared__ float sMB[32];
  __shared__ int   sIdx[32];
  __shared__ int   sShad[32];
  __shared__ float sNbr[32][3];
  __shared__ float sLrf[32][37];
  __shared__ float sW[4][15][32];
  __shared__ float sNbx[32][4][65];

  if (tid < 36) sQ[tid]  = q_lrf[(size_t)n*36 + tid];
  if (tid < 45) sKP[tid] = kp[tid];
  if (tid < 32) sMB[tid] = mlp_b[tid];
  for (int i = tid; i < 36*32; i += 256) sMW[i >> 5][i & 31] = mlp_w[i];
  if (tid < 32) {
    int idx = nbi[(size_t)n*Hh + tid];
    int sh = (idx >= NSn) ? 1 : 0;
    sShad[tid] = sh;
    sIdx[tid]  = sh ? 0 : idx;
  }
  __syncthreads();

  if (tid < 96) {
    int h = tid / 3, d = tid - h*3;
    float v = sShad[h] ? 0.f : s_pts[(size_t)sIdx[h]*3 + d];
    sNbr[h][d] = v - q_pts[(size_t)n*3 + d];
  }
  {
    int h = tid >> 3, j0 = tid & 7;
    const float* src = s_lrf + (size_t)sIdx[h]*36;
    float z = sShad[h] ? 0.f : 1.f;
    for (int j = j0; j < 36; j += 8) sLrf[h][j] = z * src[j];
  }
  for (int i = tid; i < Hh*128; i += 256) {
    int h = i >> 7, c = i & 127;
    float v = sShad[h] ? 0.f : x[(size_t)sIdx[h]*128 + c];
    sNbx[h][c >> 5][c & 31] = v;
  }
  __syncthreads();

  {
    int q = tid >> 6, l = tid & 63;
    int h = l & 31, kh = l >> 5;
    float a0 = 0.f, a1 = 0.f, a2 = 0.f;
    #pragma unroll
    for (int d = 0; d < 3; ++d) {
      float nd = sNbr[h][d];
      a0 += nd * sQ[q*9 + d*3 + 0];
      a1 += nd * sQ[q*9 + d*3 + 1];
      a2 += nd * sQ[q*9 + d*3 + 2];
    }
    float z = sShad[h] ? 0.f : 1.f;
    int k0 = kh * 8;
    int kend = k0 + (kh ? 7 : 8);
    for (int k = k0; k < kend; ++k) {
      float d0 = a0 - sKP[k*3+0];
      float d1 = a1 - sKP[k*3+1];
      float d2 = a2 - sKP[k*3+2];
      float wv2 = 1.f - sqrtf(d0*d0 + d1*d1 + d2*d2) * (1.0f/1.2f);
      sW[q][k][h] = z * fmaxf(wv2, 0.f);
    }
  }
  {
    int q = tid >> 6, l = tid & 63;
    int h = l & 31, mh = l >> 5;
    float fi[36];
    #pragma unroll
    for (int s = 0; s < 4; ++s)
      #pragma unroll
      for (int a = 0; a < 3; ++a)
        #pragma unroll
        for (int c = 0; c < 3; ++c) {
          float accv = 0.f;
          #pragma unroll
          for (int b = 0; b < 3; ++b)
            accv += sQ[q*9 + b*3 + a] * sLrf[h][s*9 + b*3 + c];
          fi[s*9 + a*3 + c] = accv;
        }
    float z = sShad[h] ? 0.f : 1.f;
    int m0 = mh * 16;
    for (int mm = 0; mm < 16; ++mm) {
      int m = m0 + mm;
      float accv = sMB[m];
      #pragma unroll
      for (int j = 0; j < 36; ++j) accv += fi[j] * sMW[j][m];
      sNbx[h][q][32 + m] = z * accv;
    }
  }
  __syncthreads();

  float acc[15];
  const int q = tid >> 6, cch = tid & 63;
  #pragma unroll
  for (int k = 0; k < 15; ++k) acc[k] = 0.f;
  for (int h = 0; h < Hh; ++h) {
    float v = sNbx[h][q][cch];
    #pragma unroll
    for (int k = 0; k < 15; ++k) acc[k] += sW[q][k][h] * v;
  }

  __shared__ float sWF[FDIM];
  __shared__ float sRed[2][128];
  #pragma unroll
  for (int k = 0; k < 15; ++k) sWF[k*256 + q*64 + cch] = acc[k];
  __syncthreads();
  int o = tid & 127, part = tid >> 7;
  const float* wp = weights + (size_t)part*1920*128 + o;
  const float* wfp = sWF + part*1920;
  float oa = 0.f;
  #pragma unroll 8
  for (int f = 0; f < 1920; ++f)
    oa += wfp[f] * wp[(size_t)f*128];
  sRed[part][o] = oa;
  __syncthreads();
  if (tid < 128) out[(size_t)n*128 + tid] = sRed[0][tid] + sRed[1][tid];
}

extern "C" void kernel_launch(void* const* d_in, const int* in_sizes, int n_in,
                              void* d_out, int out_size, void* d_ws, size_t ws_size,
                              hipStream_t stream) {
  const float* q_pts   = (const float*)d_in[0];
  const float* s_pts   = (const float*)d_in[1];
  const int*   nbi     = (const int*)  d_in[2];
  const float* x       = (const float*)d_in[3];
  const float* q_lrf   = (const float*)d_in[4];
  const float* s_lrf   = (const float*)d_in[5];
  const float* weights = (const float*)d_in[6];
  const float* kp      = (const float*)d_in[7];
  const float* mlp_w   = (const float*)d_in[8];
  const float* mlp_b   = (const float*)d_in[9];
  float* out = (float*)d_out;

  const size_t nWf  = (size_t)NQn * FDIM;             // fp16 elems
  const size_t nWt  = (size_t)128 * FDIM;
  const size_t nXh  = (size_t)(NSn + 1) * 128;
  const size_t nSlh = (size_t)(NSn + 1) * 64;
  const size_t h16  = nWf + nWt + nXh + nSlh;         // all multiples of 8
  const size_t needBytes = h16 * sizeof(_Float16)
                         + (size_t)KSPLIT * NQn * 128 * sizeof(float);
  if (ws_size >= needBytes) {
    _Float16* wf  = (_Float16*)d_ws;
    _Float16* wt  = wf + nWf;
    _Float16* xh  = wt + nWt;
    _Float16* slh = xh + nXh;
    float* cpart  = (float*)(slh + nSlh);             // 16B-aligned
    ekp_prep8<<<1146, 256, 0, stream>>>(weights, x, s_lrf, wt, xh, slh);
    ekp_stage1k<<<NQn, 256, 0, stream>>>(q_pts, s_pts, nbi,
                                         (const unsigned short*)xh,
                                         q_lrf, slh, kp, mlp_w, mlp_b, wf);
    dim3 gg((NQn + 31)/32, KSPLIT);
    ekp_gemm5<<<gg, 256, 0, stream>>>(wf, wt, cpart);
    ekp_reduce<<<NQn*128/(256*4), 256, 0, stream>>>(cpart, out);
  } else {
    ekp_stage1_fused<<<NQn, 256, 0, stream>>>(q_pts, s_pts, nbi, x, q_lrf, s_lrf,
                                              weights, kp, mlp_w, mlp_b, out);
  }
}